// Round 5
// baseline (1752.928 us; speedup 1.0000x reference)
//
#include <hip/hip_runtime.h>
#include <hip/hip_bf16.h>
#include <math.h>

// Problem constants
#define B_   2
#define L_   2048
#define HID_ 512
#define NH_  8
#define HD_  64
#define SK_  40
#define NTOP_ 40
#define NBH_ (B_ * NH_)        // 16
#define NROW_ (B_ * L_)        // 4096
#define CHUNK_ 64
#define NCH_ (L_ / CHUNK_)     // 32
#define NTILE_ 32              // 4096/128 row tiles

// ---------------------------------------------------------------------------
// Kernel 1: fused QKV projection, double-buffered LDS (1 barrier per k-step).
// C[i,j] = sum_k A[i,k]*W[j,k] + bias[j].  128x64 tile, BK=32, 8x4 micro.
// k-indexed XOR swizzle on float4 slot -> conflict-free writes + b128 reads.
// z==2 (V) writes per-tile vmean partials (no atomics).
// ---------------------------------------------------------------------------
__global__ __launch_bounds__(256, 3) void proj_kernel(
    const float* __restrict__ A,
    const float* __restrict__ Wq, const float* __restrict__ bq,
    const float* __restrict__ Wk, const float* __restrict__ bk,
    const float* __restrict__ Wv, const float* __restrict__ bv,
    float* __restrict__ qo, float* __restrict__ ko, float* __restrict__ vo,
    float* __restrict__ vmp)
{
    const float* W; const float* bias; float* out;
    if (blockIdx.z == 0)      { W = Wq; bias = bq; out = qo; }
    else if (blockIdx.z == 1) { W = Wk; bias = bk; out = ko; }
    else                      { W = Wv; bias = bv; out = vo; }

    __shared__ __align__(16) float As[2][32][132];
    __shared__ __align__(16) float Bs[2][32][68];

    const int t    = threadIdx.x;
    const int row0 = blockIdx.x * 128;
    const int h    = blockIdx.y;
    const int col0 = h * 64;
    const int ry   = t >> 4;              // 0..15 : rows ry*8 .. +7
    const int cx   = t & 15;              // 0..15 : cols cx*4 .. +3
    const int a_k4 = t & 7;
    const int sub  = t >> 3;              // 0..31

    float acc[8][4] = {};
    float4 pa[4], pb[2];

    // prologue: load + stage k-tile 0
    #pragma unroll
    for (int i = 0; i < 4; ++i)
        pa[i] = *reinterpret_cast<const float4*>(
            &A[(size_t)(row0 + i * 32 + sub) * HID_ + (a_k4 << 2)]);
    #pragma unroll
    for (int i = 0; i < 2; ++i)
        pb[i] = *reinterpret_cast<const float4*>(
            &W[(size_t)(col0 + i * 32 + sub) * HID_ + (a_k4 << 2)]);
    #pragma unroll
    for (int i = 0; i < 4; ++i) {
        const int a_row = i * 32 + sub;
        const int slot = (a_row >> 2) ^ a_k4;
        float* p = &As[0][a_k4 << 2][slot * 4 + (a_row & 3)];
        p[0 * 132] = pa[i].x; p[1 * 132] = pa[i].y;
        p[2 * 132] = pa[i].z; p[3 * 132] = pa[i].w;
    }
    #pragma unroll
    for (int i = 0; i < 2; ++i) {
        const int b_col = i * 32 + sub;
        const int slot = (b_col >> 2) ^ a_k4;
        float* p = &Bs[0][a_k4 << 2][slot * 4 + (b_col & 3)];
        p[0 * 68] = pb[i].x; p[1 * 68] = pb[i].y;
        p[2 * 68] = pb[i].z; p[3 * 68] = pb[i].w;
    }
    __syncthreads();

    for (int ks = 0; ks < 16; ++ks) {
        const int cur = ks & 1;
        // issue next tile's global loads (latency hidden under compute)
        if (ks < 15) {
            const int k0 = (ks + 1) * 32;
            #pragma unroll
            for (int i = 0; i < 4; ++i)
                pa[i] = *reinterpret_cast<const float4*>(
                    &A[(size_t)(row0 + i * 32 + sub) * HID_ + k0 + (a_k4 << 2)]);
            #pragma unroll
            for (int i = 0; i < 2; ++i)
                pb[i] = *reinterpret_cast<const float4*>(
                    &W[(size_t)(col0 + i * 32 + sub) * HID_ + k0 + (a_k4 << 2)]);
        }

        #pragma unroll
        for (int kk = 0; kk < 32; ++kk) {
            const int v = kk >> 2;
            const float4 a0 = *reinterpret_cast<const float4*>(
                &As[cur][kk][((ry * 2)     ^ v) << 2]);
            const float4 a1 = *reinterpret_cast<const float4*>(
                &As[cur][kk][((ry * 2 + 1) ^ v) << 2]);
            const float4 b0 = *reinterpret_cast<const float4*>(
                &Bs[cur][kk][(cx ^ v) << 2]);
            const float as[8] = {a0.x, a0.y, a0.z, a0.w, a1.x, a1.y, a1.z, a1.w};
            #pragma unroll
            for (int i = 0; i < 8; ++i) {
                acc[i][0] = fmaf(as[i], b0.x, acc[i][0]);
                acc[i][1] = fmaf(as[i], b0.y, acc[i][1]);
                acc[i][2] = fmaf(as[i], b0.z, acc[i][2]);
                acc[i][3] = fmaf(as[i], b0.w, acc[i][3]);
            }
        }

        // stage next tile into the other buffer
        if (ks < 15) {
            const int nxt = cur ^ 1;
            #pragma unroll
            for (int i = 0; i < 4; ++i) {
                const int a_row = i * 32 + sub;
                const int slot = (a_row >> 2) ^ a_k4;
                float* p = &As[nxt][a_k4 << 2][slot * 4 + (a_row & 3)];
                p[0 * 132] = pa[i].x; p[1 * 132] = pa[i].y;
                p[2 * 132] = pa[i].z; p[3 * 132] = pa[i].w;
            }
            #pragma unroll
            for (int i = 0; i < 2; ++i) {
                const int b_col = i * 32 + sub;
                const int slot = (b_col >> 2) ^ a_k4;
                float* p = &Bs[nxt][a_k4 << 2][slot * 4 + (b_col & 3)];
                p[0 * 68] = pb[i].x; p[1 * 68] = pb[i].y;
                p[2 * 68] = pb[i].z; p[3 * 68] = pb[i].w;
            }
            __syncthreads();
        }
    }

    const float4 bb = *reinterpret_cast<const float4*>(&bias[col0 + (cx << 2)]);
    const int b_ = row0 >> 11;            // 128-row tile lies within one batch
    #pragma unroll
    for (int i = 0; i < 8; ++i) {
        const int row = row0 + ry * 8 + i;
        const int l   = row & (L_ - 1);
        float4 ob;
        ob.x = acc[i][0] + bb.x;
        ob.y = acc[i][1] + bb.y;
        ob.z = acc[i][2] + bb.z;
        ob.w = acc[i][3] + bb.w;
        *reinterpret_cast<float4*>(
            &out[(((size_t)(b_ * NH_ + h)) * L_ + l) * HD_ + (cx << 2)]) = ob;
    }

    // fused vmean partial (V blocks only): per-tile sums, no atomics.
    // red aliases As[0] (last compute read buf 1; buf 0 last read at ks=14,
    // barrier at end of ks=14 already ordered that).
    if (blockIdx.z == 2) {
        float* red = &As[0][0][0];         // 16 x 64 floats
        #pragma unroll
        for (int j = 0; j < 4; ++j) {
            float s_ = 0.f;
            #pragma unroll
            for (int i = 0; i < 8; ++i) s_ += acc[i][j];
            const float bj = (j == 0) ? bb.x : (j == 1) ? bb.y : (j == 2) ? bb.z : bb.w;
            red[ry * 64 + (cx << 2) + j] = s_ + 8.f * bj;   // 8 rows incl. bias
        }
        __syncthreads();
        if (t < 64) {
            float s_ = 0.f;
            #pragma unroll
            for (int r = 0; r < 16; ++r) s_ += red[r * 64 + t];
            vmp[((size_t)blockIdx.x * NH_ + h) * HD_ + t] = s_;   // incl. 128*bias
        }
    }
}

// ---------------------------------------------------------------------------
// Kernel 2: vmean reduce (16 tiles) + base_out[b,j] = vmean_flat[b].Wo[j,:]+bo
// grid B_, block 512 (t = h*64+d == flat j)
// ---------------------------------------------------------------------------
__global__ __launch_bounds__(512) void base_kernel(
    const float* __restrict__ vmp, const float* __restrict__ Wo,
    const float* __restrict__ bo, float* __restrict__ vmean,
    float* __restrict__ base_out)
{
    const int b = blockIdx.x;
    const int t = threadIdx.x;           // = h*64+d = flat j
    __shared__ float vm[HID_];

    float s = 0.f;
    #pragma unroll
    for (int tl = 0; tl < 16; ++tl)
        s += vmp[((size_t)(b * 16 + tl) * NH_) * HD_ + t];   // (tile, h*64+d)
    const float mv = s * (1.0f / (float)L_);
    vmean[b * HID_ + t] = mv;
    vm[t] = mv;
    __syncthreads();

    float acc = bo[t];
    for (int c = 0; c < HID_; c += 4) {
        float4 w = *reinterpret_cast<const float4*>(&Wo[(size_t)t * HID_ + c]);
        acc = fmaf(vm[c + 0], w.x, acc);
        acc = fmaf(vm[c + 1], w.y, acc);
        acc = fmaf(vm[c + 2], w.z, acc);
        acc = fmaf(vm[c + 3], w.w, acc);
    }
    base_out[b * HID_ + t] = acc;
}

// ---------------------------------------------------------------------------
// Kernel 3: sampled scores -> m[b,h,l] = max_s(q.k_samp) - sum_s(q.k_samp)/L
// ---------------------------------------------------------------------------
__global__ __launch_bounds__(256) void sample_m_kernel(
    const float* __restrict__ q, const float* __restrict__ k,
    const int* __restrict__ idx, float* __restrict__ m)
{
    const int wid  = blockIdx.x * 4 + (threadIdx.x >> 6);
    const int lane = threadIdx.x & 63;
    const int bh = wid >> 11;
    const int l  = wid & (L_ - 1);
    const int grp = lane >> 4, gl = lane & 15;

    const float4 qf = *reinterpret_cast<const float4*>(&q[(bh * L_ + l) * HD_ + (gl << 2)]);

    float mx = -INFINITY, sm = 0.f;
    #pragma unroll
    for (int it = 0; it < 10; ++it) {
        const int s  = it * 4 + grp;
        const int ki = idx[l * SK_ + s];
        const float4 kf = *reinterpret_cast<const float4*>(&k[(bh * L_ + ki) * HD_ + (gl << 2)]);
        float p = qf.x * kf.x + qf.y * kf.y + qf.z * kf.z + qf.w * kf.w;
        p += __shfl_xor(p, 1);
        p += __shfl_xor(p, 2);
        p += __shfl_xor(p, 4);
        p += __shfl_xor(p, 8);
        mx = fmaxf(mx, p);
        sm += p;
    }
    mx = fmaxf(mx, __shfl_xor(mx, 16));
    mx = fmaxf(mx, __shfl_xor(mx, 32));
    sm += __shfl_xor(sm, 16);
    sm += __shfl_xor(sm, 32);
    if (lane == 0) m[bh * L_ + l] = mx - sm * (1.0f / (float)L_);
}

// ---------------------------------------------------------------------------
// Kernel 4: top-40 per (b,h) via 32-round bitwise binary search on the
// order-preserving uint mapping. No LDS atomics (values live in registers;
// counts via shfl reduce). Ties -> lowest index.
// ---------------------------------------------------------------------------
__global__ __launch_bounds__(256) void topk_kernel(
    const float* __restrict__ m, int* __restrict__ m_top)
{
    const int bh = blockIdx.x;
    const int t  = threadIdx.x;
    const int lane = t & 63, wv = t >> 6;

    unsigned xv[8];
    #pragma unroll
    for (int i = 0; i < 8; ++i) {
        unsigned x = __float_as_uint(m[bh * L_ + i * 256 + t]);
        xv[i] = (x & 0x80000000u) ? ~x : (x | 0x80000000u);
    }

    __shared__ int cnt[2][4];
    __shared__ int s_outcnt, s_tieCnt;
    __shared__ int tie[256];
    if (t == 0) { s_outcnt = 0; s_tieCnt = 0; }

    unsigned pref = 0;
    for (int bit = 31; bit >= 0; --bit) {
        const unsigned test = pref | (1u << bit);
        int c = 0;
        #pragma unroll
        for (int i = 0; i < 8; ++i) c += (xv[i] >= test);
        #pragma unroll
        for (int off = 1; off < 64; off <<= 1) c += __shfl_xor(c, off);
        if (lane == 0) cnt[bit & 1][wv] = c;
        __syncthreads();
        const int tot = cnt[bit & 1][0] + cnt[bit & 1][1]
                      + cnt[bit & 1][2] + cnt[bit & 1][3];
        if (tot >= NTOP_) pref = test;
    }
    const unsigned V = pref;               // 40th largest (mapped)

    #pragma unroll
    for (int i = 0; i < 8; ++i) {
        const unsigned x = xv[i];
        const int idxv = i * 256 + t;
        if (x > V) {
            const int p = atomicAdd(&s_outcnt, 1);
            m_top[bh * NTOP_ + p] = idxv;
        } else if (x == V) {
            const int p = atomicAdd(&s_tieCnt, 1);
            if (p < 256) tie[p] = idxv;
        }
    }
    __syncthreads();
    if (t == 0) {
        const int rem = NTOP_ - s_outcnt;
        int n = s_tieCnt; if (n > 256) n = 256;
        for (int r = 0; r < rem; ++r) {    // rem tiny (usually 1)
            int best = 1 << 30, bj = -1;
            for (int j2 = 0; j2 < n; ++j2)
                if (tie[j2] < best) { best = tie[j2]; bj = j2; }
            tie[bj] = 1 << 30;
            m_top[bh * NTOP_ + s_outcnt + r] = best;
        }
    }
}

// ---------------------------------------------------------------------------
// Kernel 5: chunked attention partials (flash-style).
// ---------------------------------------------------------------------------
__global__ __launch_bounds__(256) void attn_part_kernel(
    const float* __restrict__ q, const float* __restrict__ k,
    const float* __restrict__ v, const int* __restrict__ m_top,
    float* __restrict__ mx_p, float* __restrict__ sm_p, float* __restrict__ ctx_p)
{
    const int chunk = blockIdx.x;
    const int bh    = blockIdx.y;
    const int t = threadIdx.x;

    __shared__ __align__(16) float  Qs[NTOP_][64];
    __shared__ float4 Ks4[CHUNK_ * 16];
    __shared__ __align__(16) float  Vs[CHUNK_][64];
    __shared__ float  S[NTOP_][CHUNK_];

    for (int i = t; i < NTOP_ * 16; i += 256) {
        int qi = i >> 4, cc = i & 15;
        int l = m_top[bh * NTOP_ + qi];
        *reinterpret_cast<float4*>(&Qs[qi][cc << 2]) =
            *reinterpret_cast<const float4*>(&q[(bh * L_ + l) * HD_ + (cc << 2)]);
    }
    const int base = (bh * L_ + chunk * CHUNK_) * HD_;
    for (int i = t; i < CHUNK_ * 16; i += 256) {
        int r = i >> 4, cc = i & 15;
        Ks4[r * 16 + (cc ^ (r & 7))] =
            *reinterpret_cast<const float4*>(&k[base + r * HD_ + (cc << 2)]);
        *reinterpret_cast<float4*>(&Vs[r][cc << 2]) =
            *reinterpret_cast<const float4*>(&v[base + r * HD_ + (cc << 2)]);
    }
    __syncthreads();

    for (int o = t; o < NTOP_ * CHUNK_; o += 256) {
        int qi = o >> 6, j = o & (CHUNK_ - 1);
        float acc = 0.f;
        #pragma unroll
        for (int cc = 0; cc < 16; ++cc) {
            float4 kf = Ks4[j * 16 + (cc ^ (j & 7))];
            float4 qf = *reinterpret_cast<const float4*>(&Qs[qi][cc << 2]);
            acc = fmaf(qf.x, kf.x, acc);
            acc = fmaf(qf.y, kf.y, acc);
            acc = fmaf(qf.z, kf.z, acc);
            acc = fmaf(qf.w, kf.w, acc);
        }
        S[qi][j] = acc * 0.125f;
    }
    __syncthreads();

    const int gl = t & 31;
    for (int qi = t >> 5; qi < NTOP_; qi += 8) {
        float v0 = S[qi][gl], v1 = S[qi][gl + 32];
        float mx = fmaxf(v0, v1);
        #pragma unroll
        for (int off = 1; off < 32; off <<= 1) mx = fmaxf(mx, __shfl_xor(mx, off));
        float e0 = __expf(v0 - mx), e1 = __expf(v1 - mx);
        float sm = e0 + e1;
        #pragma unroll
        for (int off = 1; off < 32; off <<= 1) sm += __shfl_xor(sm, off);
        S[qi][gl] = e0; S[qi][gl + 32] = e1;
        if (gl == 0) {
            mx_p[(bh * NCH_ + chunk) * NTOP_ + qi] = mx;
            sm_p[(bh * NCH_ + chunk) * NTOP_ + qi] = sm;
        }
    }
    __syncthreads();

    for (int o = t; o < NTOP_ * HD_; o += 256) {
        int qi = o >> 6, d = o & 63;
        float acc = 0.f;
        #pragma unroll 8
        for (int j = 0; j < CHUNK_; ++j) acc = fmaf(S[qi][j], Vs[j][d], acc);
        ctx_p[((bh * NCH_ + chunk) * NTOP_ + qi) * HD_ + d] = acc;
    }
}

// ---------------------------------------------------------------------------
// Kernel 6: broadcast-fill out with base_out[b]
// ---------------------------------------------------------------------------
__global__ __launch_bounds__(256) void fill_kernel(
    const float* __restrict__ base_out, float* __restrict__ out)
{
    const int i = blockIdx.x * 256 + threadIdx.x;
    if (i >= NROW_ * (HID_ / 4)) return;
    const int j4  = i & 127;
    const int row = i >> 7;
    const int b   = row >> 11;
    reinterpret_cast<float4*>(out)[i] =
        reinterpret_cast<const float4*>(base_out)[b * 128 + j4];
}

// ---------------------------------------------------------------------------
// Kernel 7: fused combine + delta scatter.
// ---------------------------------------------------------------------------
__global__ __launch_bounds__(256) void combscat_kernel(
    const float* __restrict__ mx_p, const float* __restrict__ sm_p,
    const float* __restrict__ ctx_p, const float* __restrict__ vmean,
    const int* __restrict__ m_top, const float* __restrict__ Wo,
    float* __restrict__ out)
{
    const int bq = blockIdx.x;
    const int bh = bq / NTOP_, qi = bq % NTOP_;
    const int b = bh >> 3, h = bh & 7;
    const int t = threadIdx.x;
    const int g = t >> 6, d = t & 63;

    __shared__ float Mg[4], Dg[4];
    __shared__ float Ag[4][64];
    __shared__ float delta[64];

    float mxs[8];
    #pragma unroll
    for (int c8 = 0; c8 < 8; ++c8)
        mxs[c8] = mx_p[(bh * NCH_ + g * 8 + c8) * NTOP_ + qi];
    float M = mxs[0];
    #pragma unroll
    for (int c8 = 1; c8 < 8; ++c8) M = fmaxf(M, mxs[c8]);
    float den = 0.f, acc = 0.f;
    #pragma unroll
    for (int c8 = 0; c8 < 8; ++c8) {
        const int c = g * 8 + c8;
        const float w = __expf(mxs[c8] - M);
        den = fmaf(sm_p[(bh * NCH_ + c) * NTOP_ + qi], w, den);
        acc = fmaf(ctx_p[((bh * NCH_ + c) * NTOP_ + qi) * HD_ + d], w, acc);
    }
    if (d == 0) { Mg[g] = M; Dg[g] = den; }
    Ag[g][d] = acc;
    __syncthreads();
    if (t < 64) {
        const float MM = fmaxf(fmaxf(Mg[0], Mg[1]), fmaxf(Mg[2], Mg[3]));
        float dd = 0.f, aa = 0.f;
        #pragma unroll
        for (int gg = 0; gg < 4; ++gg) {
            const float w = __expf(Mg[gg] - MM);
            dd = fmaf(Dg[gg], w, dd);
            aa = fmaf(Ag[gg][t], w, aa);
        }
        delta[t] = aa / dd - vmean[bh * HD_ + t];
    }
    __syncthreads();
    const int l = m_top[bh * NTOP_ + qi];
    for (int j = t; j < HID_; j += 256) {
        float a2 = 0.f;
        #pragma unroll
        for (int c = 0; c < HD_; c += 4) {
            float4 w = *reinterpret_cast<const float4*>(&Wo[(size_t)j * HID_ + h * HD_ + c]);
            a2 = fmaf(delta[c + 0], w.x, a2);
            a2 = fmaf(delta[c + 1], w.y, a2);
            a2 = fmaf(delta[c + 2], w.z, a2);
            a2 = fmaf(delta[c + 3], w.w, a2);
        }
        atomicAdd(&out[((size_t)(b * L_ + l)) * HID_ + j], a2);
    }
}

// ---------------------------------------------------------------------------
extern "C" void kernel_launch(void* const* d_in, const int* in_sizes, int n_in,
                              void* d_out, int out_size, void* d_ws, size_t ws_size,
                              hipStream_t stream)
{
    const float* hs  = (const float*)d_in[0];
    const int*   idx = (const int*)  d_in[1];
    const float* Wq  = (const float*)d_in[2];
    const float* bq  = (const float*)d_in[3];
    const float* Wk  = (const float*)d_in[4];
    const float* bk  = (const float*)d_in[5];
    const float* Wv  = (const float*)d_in[6];
    const float* bv  = (const float*)d_in[7];
    const float* Wo  = (const float*)d_in[8];
    const float* bo  = (const float*)d_in[9];
    float* out = (float*)d_out;

    float* ws = (float*)d_ws;
    const size_t OFF_Q      = 0;
    const size_t OFF_K      = OFF_Q + (size_t)NBH_ * L_ * HD_;
    const size_t OFF_V      = OFF_K + (size_t)NBH_ * L_ * HD_;
    const size_t OFF_M      = OFF_V + (size_t)NBH_ * L_ * HD_;
    const size_t OFF_VMP    = OFF_M + (size_t)NBH_ * L_;            // 32*8*64
    const size_t OFF_VMEAN  = OFF_VMP + (size_t)NTILE_ * NH_ * HD_;
    const size_t OFF_MXP    = OFF_VMEAN + (size_t)NBH_ * HD_;
    const size_t OFF_SMP    = OFF_MXP + (size_t)NBH_ * NCH_ * NTOP_;
    const size_t OFF_CTXP   = OFF_SMP + (size_t)NBH_ * NCH_ * NTOP_;
    const size_t OFF_BASE   = OFF_CTXP + (size_t)NBH_ * NCH_ * NTOP_ * HD_;
    const size_t OFF_TOP    = OFF_BASE + (size_t)B_ * HID_;

    float* q_      = ws + OFF_Q;
    float* k_      = ws + OFF_K;
    float* v_      = ws + OFF_V;
    float* m_      = ws + OFF_M;
    float* vmp_    = ws + OFF_VMP;
    float* vmean_  = ws + OFF_VMEAN;
    float* mxp_    = ws + OFF_MXP;
    float* smp_    = ws + OFF_SMP;
    float* ctxp_   = ws + OFF_CTXP;
    float* base_   = ws + OFF_BASE;
    int*   mtop_   = (int*)(ws + OFF_TOP);

    proj_kernel<<<dim3(NROW_ / 128, NH_, 3), 256, 0, stream>>>(
        hs, Wq, bq, Wk, bk, Wv, bv, q_, k_, v_, vmp_);
    base_kernel<<<B_, 512, 0, stream>>>(vmp_, Wo, bo, vmean_, base_);
    sample_m_kernel<<<(NBH_ * L_) / 4, 256, 0, stream>>>(q_, k_, idx, m_);
    topk_kernel<<<NBH_, 256, 0, stream>>>(m_, mtop_);
    attn_part_kernel<<<dim3(NCH_, NBH_), 256, 0, stream>>>(
        q_, k_, v_, mtop_, mxp_, smp_, ctxp_);
    fill_kernel<<<(NROW_ * (HID_ / 4) + 255) / 256, 256, 0, stream>>>(base_, out);
    combscat_kernel<<<NBH_ * NTOP_, 256, 0, stream>>>(
        mxp_, smp_, ctxp_, vmean_, mtop_, Wo, out);
}

// Round 10
// 268.848 us; speedup vs baseline: 6.5201x; 6.5201x over previous
//
#include <hip/hip_runtime.h>
#include <hip/hip_bf16.h>
#include <math.h>

// Problem constants
#define B_   2
#define L_   2048
#define HID_ 512
#define NH_  8
#define HD_  64
#define SK_  40
#define NTOP_ 40
#define NBH_ (B_ * NH_)        // 16
#define NROW_ (B_ * L_)        // 4096
#define CHUNK_ 64
#define NCH_ (L_ / CHUNK_)     // 32
#define NTILE_ 32              // 4096/128 row tiles

// ---------------------------------------------------------------------------
// Kernel 1: QKV-merged projection. One block computes Q,K,V 128x64 tiles for
// one (row-tile, head): A-tile staged once, 3 B-tiles -> FMA:LDS ratio 96:5.
// Round-4 measured-good skeleton: single LDS buffer, reg-prefetch, 2 barriers
// per k-step (the round-5 double-buffer variant spilled to scratch: 5.5 GB/
// dispatch — do not reintroduce).
// k-indexed XOR swizzle on float4 slot -> conflict-free writes + b128 reads.
// ---------------------------------------------------------------------------
__global__ __launch_bounds__(256, 1) void proj_kernel(
    const float* __restrict__ A,
    const float* __restrict__ Wq, const float* __restrict__ bq,
    const float* __restrict__ Wk, const float* __restrict__ bk,
    const float* __restrict__ Wv, const float* __restrict__ bv,
    float* __restrict__ qo, float* __restrict__ ko, float* __restrict__ vo,
    float* __restrict__ vmp)
{
    __shared__ __align__(16) float As[32][132];      // [k][swizzled 128 rows]
    __shared__ __align__(16) float Bs[3][32][68];    // [w][k][swizzled 64 cols]
    __shared__ float red[16][64];                    // vmean partial reduce

    const float* Ws[3]  = {Wq, Wk, Wv};
    const float* bs3[3] = {bq, bk, bv};
    float*       os3[3] = {qo, ko, vo};

    const int t    = threadIdx.x;
    const int row0 = blockIdx.x * 128;
    const int h    = blockIdx.y;
    const int col0 = h * 64;
    const int ry   = t >> 4;              // 0..15 : rows ry*8 .. +7
    const int cx   = t & 15;              // 0..15 : cols cx*4 .. +3
    const int a_k4 = t & 7;               // float4-group along k
    const int sub  = t >> 3;              // 0..31

    float acc[3][8][4] = {};
    float4 pa[4], pb[3][2];

    // prologue: load k-tile 0 into registers
    #pragma unroll
    for (int i = 0; i < 4; ++i)
        pa[i] = *reinterpret_cast<const float4*>(
            &A[(size_t)(row0 + i * 32 + sub) * HID_ + (a_k4 << 2)]);
    #pragma unroll
    for (int w = 0; w < 3; ++w)
        #pragma unroll
        for (int i = 0; i < 2; ++i)
            pb[w][i] = *reinterpret_cast<const float4*>(
                &Ws[w][(size_t)(col0 + i * 32 + sub) * HID_ + (a_k4 << 2)]);

    for (int ks = 0; ks < 16; ++ks) {
        // store prefetched regs -> LDS (swizzled)
        #pragma unroll
        for (int i = 0; i < 4; ++i) {
            const int a_row = i * 32 + sub;
            const int slot = (a_row >> 2) ^ a_k4;
            float* p = &As[a_k4 << 2][slot * 4 + (a_row & 3)];
            p[0 * 132] = pa[i].x; p[1 * 132] = pa[i].y;
            p[2 * 132] = pa[i].z; p[3 * 132] = pa[i].w;
        }
        #pragma unroll
        for (int w = 0; w < 3; ++w)
            #pragma unroll
            for (int i = 0; i < 2; ++i) {
                const int b_col = i * 32 + sub;
                const int slot = (b_col >> 2) ^ a_k4;
                float* p = &Bs[w][a_k4 << 2][slot * 4 + (b_col & 3)];
                p[0 * 68] = pb[w][i].x; p[1 * 68] = pb[w][i].y;
                p[2 * 68] = pb[w][i].z; p[3 * 68] = pb[w][i].w;
            }
        __syncthreads();

        // issue next tile's global loads; latency covered by the 32-kk compute
        if (ks < 15) {
            const int k0 = (ks + 1) * 32;
            #pragma unroll
            for (int i = 0; i < 4; ++i)
                pa[i] = *reinterpret_cast<const float4*>(
                    &A[(size_t)(row0 + i * 32 + sub) * HID_ + k0 + (a_k4 << 2)]);
            #pragma unroll
            for (int w = 0; w < 3; ++w)
                #pragma unroll
                for (int i = 0; i < 2; ++i)
                    pb[w][i] = *reinterpret_cast<const float4*>(
                        &Ws[w][(size_t)(col0 + i * 32 + sub) * HID_ + k0 + (a_k4 << 2)]);
        }

        #pragma unroll
        for (int kk = 0; kk < 32; ++kk) {
            const int v = kk >> 2;
            const float4 a0 = *reinterpret_cast<const float4*>(
                &As[kk][((ry * 2)     ^ v) << 2]);
            const float4 a1 = *reinterpret_cast<const float4*>(
                &As[kk][((ry * 2 + 1) ^ v) << 2]);
            const float as[8] = {a0.x, a0.y, a0.z, a0.w, a1.x, a1.y, a1.z, a1.w};
            #pragma unroll
            for (int w = 0; w < 3; ++w) {
                const float4 b0 = *reinterpret_cast<const float4*>(
                    &Bs[w][kk][(cx ^ v) << 2]);
                #pragma unroll
                for (int i = 0; i < 8; ++i) {
                    acc[w][i][0] = fmaf(as[i], b0.x, acc[w][i][0]);
                    acc[w][i][1] = fmaf(as[i], b0.y, acc[w][i][1]);
                    acc[w][i][2] = fmaf(as[i], b0.z, acc[w][i][2]);
                    acc[w][i][3] = fmaf(as[i], b0.w, acc[w][i][3]);
                }
            }
        }
        __syncthreads();
    }

    const int b_ = row0 >> 11;            // 128-row tile lies within one batch
    float4 bbv;                            // V bias, reused by vmean tail
    #pragma unroll
    for (int w = 0; w < 3; ++w) {
        const float4 bb = *reinterpret_cast<const float4*>(&bs3[w][col0 + (cx << 2)]);
        if (w == 2) bbv = bb;
        #pragma unroll
        for (int i = 0; i < 8; ++i) {
            const int row = row0 + ry * 8 + i;
            const int l   = row & (L_ - 1);
            float4 ob;
            ob.x = acc[w][i][0] + bb.x;
            ob.y = acc[w][i][1] + bb.y;
            ob.z = acc[w][i][2] + bb.z;
            ob.w = acc[w][i][3] + bb.w;
            *reinterpret_cast<float4*>(
                &os3[w][(((size_t)(b_ * NH_ + h)) * L_ + l) * HD_ + (cx << 2)]) = ob;
        }
    }

    // fused vmean partial: per-tile sums of V (incl. bias), no atomics
    #pragma unroll
    for (int j = 0; j < 4; ++j) {
        float s_ = 0.f;
        #pragma unroll
        for (int i = 0; i < 8; ++i) s_ += acc[2][i][j];
        const float bj = (j == 0) ? bbv.x : (j == 1) ? bbv.y : (j == 2) ? bbv.z : bbv.w;
        red[ry][(cx << 2) + j] = s_ + 8.f * bj;
    }
    __syncthreads();
    if (t < 64) {
        float s_ = 0.f;
        #pragma unroll
        for (int r = 0; r < 16; ++r) s_ += red[r][t];
        vmp[((size_t)blockIdx.x * NH_ + h) * HD_ + t] = s_;    // incl. 128*bias
    }
}

// ---------------------------------------------------------------------------
// Kernel 2: vmean reduce (16 tiles) + base_out[b,j] = vmean_flat[b].Wo[j,:]+bo
// grid B_, block 512 (t = h*64+d == flat j)
// ---------------------------------------------------------------------------
__global__ __launch_bounds__(512) void base_kernel(
    const float* __restrict__ vmp, const float* __restrict__ Wo,
    const float* __restrict__ bo, float* __restrict__ vmean,
    float* __restrict__ base_out)
{
    const int b = blockIdx.x;
    const int t = threadIdx.x;           // = h*64+d = flat j
    __shared__ float vm[HID_];

    float s = 0.f;
    #pragma unroll
    for (int tl = 0; tl < 16; ++tl)
        s += vmp[((size_t)(b * 16 + tl) * NH_) * HD_ + t];   // tile*512 + t
    const float mv = s * (1.0f / (float)L_);
    vmean[b * HID_ + t] = mv;
    vm[t] = mv;
    __syncthreads();

    float acc = bo[t];
    for (int c = 0; c < HID_; c += 4) {
        float4 w = *reinterpret_cast<const float4*>(&Wo[(size_t)t * HID_ + c]);
        acc = fmaf(vm[c + 0], w.x, acc);
        acc = fmaf(vm[c + 1], w.y, acc);
        acc = fmaf(vm[c + 2], w.z, acc);
        acc = fmaf(vm[c + 3], w.w, acc);
    }
    base_out[b * HID_ + t] = acc;
}

// ---------------------------------------------------------------------------
// Kernel 3: sampled scores -> m[b,h,l] = max_s(q.k_samp) - sum_s(q.k_samp)/L
// ---------------------------------------------------------------------------
__global__ __launch_bounds__(256) void sample_m_kernel(
    const float* __restrict__ q, const float* __restrict__ k,
    const int* __restrict__ idx, float* __restrict__ m)
{
    const int wid  = blockIdx.x * 4 + (threadIdx.x >> 6);
    const int lane = threadIdx.x & 63;
    const int bh = wid >> 11;
    const int l  = wid & (L_ - 1);
    const int grp = lane >> 4, gl = lane & 15;

    const float4 qf = *reinterpret_cast<const float4*>(&q[(bh * L_ + l) * HD_ + (gl << 2)]);

    float mx = -INFINITY, sm = 0.f;
    #pragma unroll
    for (int it = 0; it < 10; ++it) {
        const int s  = it * 4 + grp;
        const int ki = idx[l * SK_ + s];
        const float4 kf = *reinterpret_cast<const float4*>(&k[(bh * L_ + ki) * HD_ + (gl << 2)]);
        float p = qf.x * kf.x + qf.y * kf.y + qf.z * kf.z + qf.w * kf.w;
        p += __shfl_xor(p, 1);
        p += __shfl_xor(p, 2);
        p += __shfl_xor(p, 4);
        p += __shfl_xor(p, 8);
        mx = fmaxf(mx, p);
        sm += p;
    }
    mx = fmaxf(mx, __shfl_xor(mx, 16));
    mx = fmaxf(mx, __shfl_xor(mx, 32));
    sm += __shfl_xor(sm, 16);
    sm += __shfl_xor(sm, 32);
    if (lane == 0) m[bh * L_ + l] = mx - sm * (1.0f / (float)L_);
}

// ---------------------------------------------------------------------------
// Kernel 4: top-40 per (b,h) via 32-round bitwise binary search on the
// order-preserving uint mapping. No LDS atomics in the search; ties -> lowest.
// ---------------------------------------------------------------------------
__global__ __launch_bounds__(256) void topk_kernel(
    const float* __restrict__ m, int* __restrict__ m_top)
{
    const int bh = blockIdx.x;
    const int t  = threadIdx.x;
    const int lane = t & 63, wv = t >> 6;

    unsigned xv[8];
    #pragma unroll
    for (int i = 0; i < 8; ++i) {
        unsigned x = __float_as_uint(m[bh * L_ + i * 256 + t]);
        xv[i] = (x & 0x80000000u) ? ~x : (x | 0x80000000u);
    }

    __shared__ int cnt[2][4];
    __shared__ int s_outcnt, s_tieCnt;
    __shared__ int tie[256];
    if (t == 0) { s_outcnt = 0; s_tieCnt = 0; }

    unsigned pref = 0;
    for (int bit = 31; bit >= 0; --bit) {
        const unsigned test = pref | (1u << bit);
        int c = 0;
        #pragma unroll
        for (int i = 0; i < 8; ++i) c += (xv[i] >= test);
        #pragma unroll
        for (int off = 1; off < 64; off <<= 1) c += __shfl_xor(c, off);
        if (lane == 0) cnt[bit & 1][wv] = c;
        __syncthreads();
        const int tot = cnt[bit & 1][0] + cnt[bit & 1][1]
                      + cnt[bit & 1][2] + cnt[bit & 1][3];
        if (tot >= NTOP_) pref = test;
    }
    const unsigned V = pref;               // 40th largest (mapped)

    #pragma unroll
    for (int i = 0; i < 8; ++i) {
        const unsigned x = xv[i];
        const int idxv = i * 256 + t;
        if (x > V) {
            const int p = atomicAdd(&s_outcnt, 1);
            m_top[bh * NTOP_ + p] = idxv;
        } else if (x == V) {
            const int p = atomicAdd(&s_tieCnt, 1);
            if (p < 256) tie[p] = idxv;
        }
    }
    __syncthreads();
    if (t == 0) {
        const int rem = NTOP_ - s_outcnt;
        int n = s_tieCnt; if (n > 256) n = 256;
        for (int r = 0; r < rem; ++r) {    // rem tiny (usually 1)
            int best = 1 << 30, bj = -1;
            for (int j2 = 0; j2 < n; ++j2)
                if (tie[j2] < best) { best = tie[j2]; bj = j2; }
            tie[bj] = 1 << 30;
            m_top[bh * NTOP_ + s_outcnt + r] = best;
        }
    }
}

// ---------------------------------------------------------------------------
// Kernel 5: chunked attention partials (flash-style).
// ---------------------------------------------------------------------------
__global__ __launch_bounds__(256) void attn_part_kernel(
    const float* __restrict__ q, const float* __restrict__ k,
    const float* __restrict__ v, const int* __restrict__ m_top,
    float* __restrict__ mx_p, float* __restrict__ sm_p, float* __restrict__ ctx_p)
{
    const int chunk = blockIdx.x;
    const int bh    = blockIdx.y;
    const int t = threadIdx.x;

    __shared__ __align__(16) float  Qs[NTOP_][64];
    __shared__ float4 Ks4[CHUNK_ * 16];
    __shared__ __align__(16) float  Vs[CHUNK_][64];
    __shared__ float  S[NTOP_][CHUNK_];

    for (int i = t; i < NTOP_ * 16; i += 256) {
        int qi = i >> 4, cc = i & 15;
        int l = m_top[bh * NTOP_ + qi];
        *reinterpret_cast<float4*>(&Qs[qi][cc << 2]) =
            *reinterpret_cast<const float4*>(&q[(bh * L_ + l) * HD_ + (cc << 2)]);
    }
    const int base = (bh * L_ + chunk * CHUNK_) * HD_;
    for (int i = t; i < CHUNK_ * 16; i += 256) {
        int r = i >> 4, cc = i & 15;
        Ks4[r * 16 + (cc ^ (r & 7))] =
            *reinterpret_cast<const float4*>(&k[base + r * HD_ + (cc << 2)]);
        *reinterpret_cast<float4*>(&Vs[r][cc << 2]) =
            *reinterpret_cast<const float4*>(&v[base + r * HD_ + (cc << 2)]);
    }
    __syncthreads();

    for (int o = t; o < NTOP_ * CHUNK_; o += 256) {
        int qi = o >> 6, j = o & (CHUNK_ - 1);
        float acc = 0.f;
        #pragma unroll
        for (int cc = 0; cc < 16; ++cc) {
            float4 kf = Ks4[j * 16 + (cc ^ (j & 7))];
            float4 qf = *reinterpret_cast<const float4*>(&Qs[qi][cc << 2]);
            acc = fmaf(qf.x, kf.x, acc);
            acc = fmaf(qf.y, kf.y, acc);
            acc = fmaf(qf.z, kf.z, acc);
            acc = fmaf(qf.w, kf.w, acc);
        }
        S[qi][j] = acc * 0.125f;
    }
    __syncthreads();

    const int gl = t & 31;
    for (int qi = t >> 5; qi < NTOP_; qi += 8) {
        float v0 = S[qi][gl], v1 = S[qi][gl + 32];
        float mx = fmaxf(v0, v1);
        #pragma unroll
        for (int off = 1; off < 32; off <<= 1) mx = fmaxf(mx, __shfl_xor(mx, off));
        float e0 = __expf(v0 - mx), e1 = __expf(v1 - mx);
        float sm = e0 + e1;
        #pragma unroll
        for (int off = 1; off < 32; off <<= 1) sm += __shfl_xor(sm, off);
        S[qi][gl] = e0; S[qi][gl + 32] = e1;
        if (gl == 0) {
            mx_p[(bh * NCH_ + chunk) * NTOP_ + qi] = mx;
            sm_p[(bh * NCH_ + chunk) * NTOP_ + qi] = sm;
        }
    }
    __syncthreads();

    for (int o = t; o < NTOP_ * HD_; o += 256) {
        int qi = o >> 6, d = o & 63;
        float acc = 0.f;
        #pragma unroll 8
        for (int j = 0; j < CHUNK_; ++j) acc = fmaf(S[qi][j], Vs[j][d], acc);
        ctx_p[((bh * NCH_ + chunk) * NTOP_ + qi) * HD_ + d] = acc;
    }
}

// ---------------------------------------------------------------------------
// Kernel 6: broadcast-fill out with base_out[b]
// ---------------------------------------------------------------------------
__global__ __launch_bounds__(256) void fill_kernel(
    const float* __restrict__ base_out, float* __restrict__ out)
{
    const int i = blockIdx.x * 256 + threadIdx.x;
    if (i >= NROW_ * (HID_ / 4)) return;
    const int j4  = i & 127;
    const int row = i >> 7;
    const int b   = row >> 11;
    reinterpret_cast<float4*>(out)[i] =
        reinterpret_cast<const float4*>(base_out)[b * 128 + j4];
}

// ---------------------------------------------------------------------------
// Kernel 7: fused combine + delta scatter.
// ---------------------------------------------------------------------------
__global__ __launch_bounds__(256) void combscat_kernel(
    const float* __restrict__ mx_p, const float* __restrict__ sm_p,
    const float* __restrict__ ctx_p, const float* __restrict__ vmean,
    const int* __restrict__ m_top, const float* __restrict__ Wo,
    float* __restrict__ out)
{
    const int bq = blockIdx.x;
    const int bh = bq / NTOP_, qi = bq % NTOP_;
    const int b = bh >> 3, h = bh & 7;
    const int t = threadIdx.x;
    const int g = t >> 6, d = t & 63;

    __shared__ float Mg[4], Dg[4];
    __shared__ float Ag[4][64];
    __shared__ float delta[64];

    float mxs[8];
    #pragma unroll
    for (int c8 = 0; c8 < 8; ++c8)
        mxs[c8] = mx_p[(bh * NCH_ + g * 8 + c8) * NTOP_ + qi];
    float M = mxs[0];
    #pragma unroll
    for (int c8 = 1; c8 < 8; ++c8) M = fmaxf(M, mxs[c8]);
    float den = 0.f, acc = 0.f;
    #pragma unroll
    for (int c8 = 0; c8 < 8; ++c8) {
        const int c = g * 8 + c8;
        const float w = __expf(mxs[c8] - M);
        den = fmaf(sm_p[(bh * NCH_ + c) * NTOP_ + qi], w, den);
        acc = fmaf(ctx_p[((bh * NCH_ + c) * NTOP_ + qi) * HD_ + d], w, acc);
    }
    if (d == 0) { Mg[g] = M; Dg[g] = den; }
    Ag[g][d] = acc;
    __syncthreads();
    if (t < 64) {
        const float MM = fmaxf(fmaxf(Mg[0], Mg[1]), fmaxf(Mg[2], Mg[3]));
        float dd = 0.f, aa = 0.f;
        #pragma unroll
        for (int gg = 0; gg < 4; ++gg) {
            const float w = __expf(Mg[gg] - MM);
            dd = fmaf(Dg[gg], w, dd);
            aa = fmaf(Ag[gg][t], w, aa);
        }
        delta[t] = aa / dd - vmean[bh * HD_ + t];
    }
    __syncthreads();
    const int l = m_top[bh * NTOP_ + qi];
    for (int j = t; j < HID_; j += 256) {
        float a2 = 0.f;
        #pragma unroll
        for (int c = 0; c < HD_; c += 4) {
            float4 w = *reinterpret_cast<const float4*>(&Wo[(size_t)j * HID_ + h * HD_ + c]);
            a2 = fmaf(delta[c + 0], w.x, a2);
            a2 = fmaf(delta[c + 1], w.y, a2);
            a2 = fmaf(delta[c + 2], w.z, a2);
            a2 = fmaf(delta[c + 3], w.w, a2);
        }
        atomicAdd(&out[((size_t)(b * L_ + l)) * HID_ + j], a2);
    }
}

// ---------------------------------------------------------------------------
extern "C" void kernel_launch(void* const* d_in, const int* in_sizes, int n_in,
                              void* d_out, int out_size, void* d_ws, size_t ws_size,
                              hipStream_t stream)
{
    const float* hs  = (const float*)d_in[0];
    const int*   idx = (const int*)  d_in[1];
    const float* Wq  = (const float*)d_in[2];
    const float* bq  = (const float*)d_in[3];
    const float* Wk  = (const float*)d_in[4];
    const float* bk  = (const float*)d_in[5];
    const float* Wv  = (const float*)d_in[6];
    const float* bv  = (const float*)d_in[7];
    const float* Wo  = (const float*)d_in[8];
    const float* bo  = (const float*)d_in[9];
    float* out = (float*)d_out;

    float* ws = (float*)d_ws;
    const size_t OFF_Q      = 0;
    const size_t OFF_K      = OFF_Q + (size_t)NBH_ * L_ * HD_;
    const size_t OFF_V      = OFF_K + (size_t)NBH_ * L_ * HD_;
    const size_t OFF_M      = OFF_V + (size_t)NBH_ * L_ * HD_;
    const size_t OFF_VMP    = OFF_M + (size_t)NBH_ * L_;
    const size_t OFF_VMEAN  = OFF_VMP + (size_t)NTILE_ * NH_ * HD_;
    const size_t OFF_MXP    = OFF_VMEAN + (size_t)NBH_ * HD_;
    const size_t OFF_SMP    = OFF_MXP + (size_t)NBH_ * NCH_ * NTOP_;
    const size_t OFF_CTXP   = OFF_SMP + (size_t)NBH_ * NCH_ * NTOP_;
    const size_t OFF_BASE   = OFF_CTXP + (size_t)NBH_ * NCH_ * NTOP_ * HD_;
    const size_t OFF_TOP    = OFF_BASE + (size_t)B_ * HID_;

    float* q_      = ws + OFF_Q;
    float* k_      = ws + OFF_K;
    float* v_      = ws + OFF_V;
    float* m_      = ws + OFF_M;
    float* vmp_    = ws + OFF_VMP;
    float* vmean_  = ws + OFF_VMEAN;
    float* mxp_    = ws + OFF_MXP;
    float* smp_    = ws + OFF_SMP;
    float* ctxp_   = ws + OFF_CTXP;
    float* base_   = ws + OFF_BASE;
    int*   mtop_   = (int*)(ws + OFF_TOP);

    proj_kernel<<<dim3(NROW_ / 128, NH_), 256, 0, stream>>>(
        hs, Wq, bq, Wk, bk, Wv, bv, q_, k_, v_, vmp_);
    base_kernel<<<B_, 512, 0, stream>>>(vmp_, Wo, bo, vmean_, base_);
    sample_m_kernel<<<(NBH_ * L_) / 4, 256, 0, stream>>>(q_, k_, idx, m_);
    topk_kernel<<<NBH_, 256, 0, stream>>>(m_, mtop_);
    attn_part_kernel<<<dim3(NCH_, NBH_), 256, 0, stream>>>(
        q_, k_, v_, mtop_, mxp_, smp_, ctxp_);
    fill_kernel<<<(NROW_ * (HID_ / 4) + 255) / 256, 256, 0, stream>>>(base_, out);
    combscat_kernel<<<NBH_ * NTOP_, 256, 0, stream>>>(
        mxp_, smp_, ctxp_, vmean_, mtop_, Wo, out);
}

// Round 11
// 258.080 us; speedup vs baseline: 6.7922x; 1.0417x over previous
//
#include <hip/hip_runtime.h>
#include <hip/hip_bf16.h>
#include <math.h>

// Problem constants
#define B_   2
#define L_   2048
#define HID_ 512
#define NH_  8
#define HD_  64
#define SK_  40
#define NTOP_ 40
#define NBH_ (B_ * NH_)        // 16
#define NROW_ (B_ * L_)        // 4096
#define CHUNK_ 64
#define NCH_ (L_ / CHUNK_)     // 32
#define NTILE_ 64              // 4096/64 row tiles

// ---------------------------------------------------------------------------
// Kernel 1: QKV-merged projection, 64-row tiles for occupancy.
// One block: Q,K,V 64x64 tiles for one (row-tile, head). 4x4 micro-tile,
// acc[3][4][4]=48 regs. Grid 64x8=512 blocks = 2/CU = 2 waves/SIMD (round-10
// showed 128-row merged @1 block/CU stalls at 44% VALU from zero TLP).
// k-indexed XOR swizzle on float4 slot -> conflict-free writes + b128 reads
// (same structure as the round-2/4 measured-zero-conflict layout).
// ---------------------------------------------------------------------------
__global__ __launch_bounds__(256, 2) void proj_kernel(
    const float* __restrict__ A,
    const float* __restrict__ Wq, const float* __restrict__ bq,
    const float* __restrict__ Wk, const float* __restrict__ bk,
    const float* __restrict__ Wv, const float* __restrict__ bv,
    float* __restrict__ qo, float* __restrict__ ko, float* __restrict__ vo,
    float* __restrict__ vmp)
{
    __shared__ __align__(16) float As[32][68];       // [k][swizzled 64 rows]
    __shared__ __align__(16) float Bs[3][32][68];    // [w][k][swizzled 64 cols]
    __shared__ float red[16][64];                    // vmean partial reduce

    const float* Ws[3]  = {Wq, Wk, Wv};
    const float* bs3[3] = {bq, bk, bv};
    float*       os3[3] = {qo, ko, vo};

    const int t    = threadIdx.x;
    const int row0 = blockIdx.x * 64;
    const int h    = blockIdx.y;
    const int col0 = h * 64;
    const int ry   = t >> 4;              // 0..15 : rows ry*4 .. +3
    const int cx   = t & 15;              // 0..15 : cols cx*4 .. +3
    const int a_k4 = t & 7;               // float4-group along k
    const int sub  = t >> 3;              // 0..31

    float acc[3][4][4] = {};
    float4 pa[2], pb[3][2];

    // prologue: load k-tile 0 into registers
    #pragma unroll
    for (int i = 0; i < 2; ++i)
        pa[i] = *reinterpret_cast<const float4*>(
            &A[(size_t)(row0 + i * 32 + sub) * HID_ + (a_k4 << 2)]);
    #pragma unroll
    for (int w = 0; w < 3; ++w)
        #pragma unroll
        for (int i = 0; i < 2; ++i)
            pb[w][i] = *reinterpret_cast<const float4*>(
                &Ws[w][(size_t)(col0 + i * 32 + sub) * HID_ + (a_k4 << 2)]);

    for (int ks = 0; ks < 16; ++ks) {
        // store prefetched regs -> LDS (swizzled)
        #pragma unroll
        for (int i = 0; i < 2; ++i) {
            const int a_row = i * 32 + sub;           // 0..63
            const int slot = (a_row >> 2) ^ a_k4;     // 0..15
            float* p = &As[a_k4 << 2][slot * 4 + (a_row & 3)];
            p[0 * 68] = pa[i].x; p[1 * 68] = pa[i].y;
            p[2 * 68] = pa[i].z; p[3 * 68] = pa[i].w;
        }
        #pragma unroll
        for (int w = 0; w < 3; ++w)
            #pragma unroll
            for (int i = 0; i < 2; ++i) {
                const int b_col = i * 32 + sub;
                const int slot = (b_col >> 2) ^ a_k4;
                float* p = &Bs[w][a_k4 << 2][slot * 4 + (b_col & 3)];
                p[0 * 68] = pb[w][i].x; p[1 * 68] = pb[w][i].y;
                p[2 * 68] = pb[w][i].z; p[3 * 68] = pb[w][i].w;
            }
        __syncthreads();

        // issue next tile's global loads; latency covered by the 32-kk compute
        if (ks < 15) {
            const int k0 = (ks + 1) * 32;
            #pragma unroll
            for (int i = 0; i < 2; ++i)
                pa[i] = *reinterpret_cast<const float4*>(
                    &A[(size_t)(row0 + i * 32 + sub) * HID_ + k0 + (a_k4 << 2)]);
            #pragma unroll
            for (int w = 0; w < 3; ++w)
                #pragma unroll
                for (int i = 0; i < 2; ++i)
                    pb[w][i] = *reinterpret_cast<const float4*>(
                        &Ws[w][(size_t)(col0 + i * 32 + sub) * HID_ + k0 + (a_k4 << 2)]);
        }

        #pragma unroll
        for (int kk = 0; kk < 32; ++kk) {
            const int v = kk >> 2;
            const float4 a0 = *reinterpret_cast<const float4*>(
                &As[kk][(ry ^ v) << 2]);              // rows ry*4 .. +3
            const float as[4] = {a0.x, a0.y, a0.z, a0.w};
            #pragma unroll
            for (int w = 0; w < 3; ++w) {
                const float4 b0 = *reinterpret_cast<const float4*>(
                    &Bs[w][kk][(cx ^ v) << 2]);       // cols cx*4 .. +3
                #pragma unroll
                for (int i = 0; i < 4; ++i) {
                    acc[w][i][0] = fmaf(as[i], b0.x, acc[w][i][0]);
                    acc[w][i][1] = fmaf(as[i], b0.y, acc[w][i][1]);
                    acc[w][i][2] = fmaf(as[i], b0.z, acc[w][i][2]);
                    acc[w][i][3] = fmaf(as[i], b0.w, acc[w][i][3]);
                }
            }
        }
        __syncthreads();
    }

    const int b_ = row0 >> 11;            // 64-row tile lies within one batch
    float4 bbv;                            // V bias, reused by vmean tail
    #pragma unroll
    for (int w = 0; w < 3; ++w) {
        const float4 bb = *reinterpret_cast<const float4*>(&bs3[w][col0 + (cx << 2)]);
        if (w == 2) bbv = bb;
        #pragma unroll
        for (int i = 0; i < 4; ++i) {
            const int row = row0 + ry * 4 + i;
            const int l   = row & (L_ - 1);
            float4 ob;
            ob.x = acc[w][i][0] + bb.x;
            ob.y = acc[w][i][1] + bb.y;
            ob.z = acc[w][i][2] + bb.z;
            ob.w = acc[w][i][3] + bb.w;
            *reinterpret_cast<float4*>(
                &os3[w][(((size_t)(b_ * NH_ + h)) * L_ + l) * HD_ + (cx << 2)]) = ob;
        }
    }

    // fused vmean partial: per-tile sums of V (incl. bias), no atomics
    #pragma unroll
    for (int j = 0; j < 4; ++j) {
        float s_ = 0.f;
        #pragma unroll
        for (int i = 0; i < 4; ++i) s_ += acc[2][i][j];
        const float bj = (j == 0) ? bbv.x : (j == 1) ? bbv.y : (j == 2) ? bbv.z : bbv.w;
        red[ry][(cx << 2) + j] = s_ + 4.f * bj;       // 4 rows incl. bias
    }
    __syncthreads();
    if (t < 64) {
        float s_ = 0.f;
        #pragma unroll
        for (int r = 0; r < 16; ++r) s_ += red[r][t];
        vmp[((size_t)blockIdx.x * NH_ + h) * HD_ + t] = s_;    // incl. 64*bias
    }
}

// ---------------------------------------------------------------------------
// Kernel 2: vmean reduce (32 tiles/batch) + base_out[b,j] = vmean.Wo[j,:]+bo
// grid B_, block 512 (t = h*64+d == flat j)
// ---------------------------------------------------------------------------
__global__ __launch_bounds__(512) void base_kernel(
    const float* __restrict__ vmp, const float* __restrict__ Wo,
    const float* __restrict__ bo, float* __restrict__ vmean,
    float* __restrict__ base_out)
{
    const int b = blockIdx.x;
    const int t = threadIdx.x;           // = h*64+d = flat j
    __shared__ float vm[HID_];

    float s = 0.f;
    #pragma unroll
    for (int tl = 0; tl < 32; ++tl)
        s += vmp[((size_t)(b * 32 + tl) * NH_) * HD_ + t];   // tile*512 + t
    const float mv = s * (1.0f / (float)L_);
    vmean[b * HID_ + t] = mv;
    vm[t] = mv;
    __syncthreads();

    float acc = bo[t];
    for (int c = 0; c < HID_; c += 4) {
        float4 w = *reinterpret_cast<const float4*>(&Wo[(size_t)t * HID_ + c]);
        acc = fmaf(vm[c + 0], w.x, acc);
        acc = fmaf(vm[c + 1], w.y, acc);
        acc = fmaf(vm[c + 2], w.z, acc);
        acc = fmaf(vm[c + 3], w.w, acc);
    }
    base_out[b * HID_ + t] = acc;
}

// ---------------------------------------------------------------------------
// Kernel 3: sampled scores -> m[b,h,l] = max_s(q.k_samp) - sum_s(q.k_samp)/L
// ---------------------------------------------------------------------------
__global__ __launch_bounds__(256) void sample_m_kernel(
    const float* __restrict__ q, const float* __restrict__ k,
    const int* __restrict__ idx, float* __restrict__ m)
{
    const int wid  = blockIdx.x * 4 + (threadIdx.x >> 6);
    const int lane = threadIdx.x & 63;
    const int bh = wid >> 11;
    const int l  = wid & (L_ - 1);
    const int grp = lane >> 4, gl = lane & 15;

    const float4 qf = *reinterpret_cast<const float4*>(&q[(bh * L_ + l) * HD_ + (gl << 2)]);

    float mx = -INFINITY, sm = 0.f;
    #pragma unroll
    for (int it = 0; it < 10; ++it) {
        const int s  = it * 4 + grp;
        const int ki = idx[l * SK_ + s];
        const float4 kf = *reinterpret_cast<const float4*>(&k[(bh * L_ + ki) * HD_ + (gl << 2)]);
        float p = qf.x * kf.x + qf.y * kf.y + qf.z * kf.z + qf.w * kf.w;
        p += __shfl_xor(p, 1);
        p += __shfl_xor(p, 2);
        p += __shfl_xor(p, 4);
        p += __shfl_xor(p, 8);
        mx = fmaxf(mx, p);
        sm += p;
    }
    mx = fmaxf(mx, __shfl_xor(mx, 16));
    mx = fmaxf(mx, __shfl_xor(mx, 32));
    sm += __shfl_xor(sm, 16);
    sm += __shfl_xor(sm, 32);
    if (lane == 0) m[bh * L_ + l] = mx - sm * (1.0f / (float)L_);
}

// ---------------------------------------------------------------------------
// Kernel 4: top-40 per (b,h) via 32-round bitwise binary search on the
// order-preserving uint mapping. No LDS atomics in the search; ties -> lowest.
// ---------------------------------------------------------------------------
__global__ __launch_bounds__(256) void topk_kernel(
    const float* __restrict__ m, int* __restrict__ m_top)
{
    const int bh = blockIdx.x;
    const int t  = threadIdx.x;
    const int lane = t & 63, wv = t >> 6;

    unsigned xv[8];
    #pragma unroll
    for (int i = 0; i < 8; ++i) {
        unsigned x = __float_as_uint(m[bh * L_ + i * 256 + t]);
        xv[i] = (x & 0x80000000u) ? ~x : (x | 0x80000000u);
    }

    __shared__ int cnt[2][4];
    __shared__ int s_outcnt, s_tieCnt;
    __shared__ int tie[256];
    if (t == 0) { s_outcnt = 0; s_tieCnt = 0; }

    unsigned pref = 0;
    for (int bit = 31; bit >= 0; --bit) {
        const unsigned test = pref | (1u << bit);
        int c = 0;
        #pragma unroll
        for (int i = 0; i < 8; ++i) c += (xv[i] >= test);
        #pragma unroll
        for (int off = 1; off < 64; off <<= 1) c += __shfl_xor(c, off);
        if (lane == 0) cnt[bit & 1][wv] = c;
        __syncthreads();
        const int tot = cnt[bit & 1][0] + cnt[bit & 1][1]
                      + cnt[bit & 1][2] + cnt[bit & 1][3];
        if (tot >= NTOP_) pref = test;
    }
    const unsigned V = pref;               // 40th largest (mapped)

    #pragma unroll
    for (int i = 0; i < 8; ++i) {
        const unsigned x = xv[i];
        const int idxv = i * 256 + t;
        if (x > V) {
            const int p = atomicAdd(&s_outcnt, 1);
            m_top[bh * NTOP_ + p] = idxv;
        } else if (x == V) {
            const int p = atomicAdd(&s_tieCnt, 1);
            if (p < 256) tie[p] = idxv;
        }
    }
    __syncthreads();
    if (t == 0) {
        const int rem = NTOP_ - s_outcnt;
        int n = s_tieCnt; if (n > 256) n = 256;
        for (int r = 0; r < rem; ++r) {    // rem tiny (usually 1)
            int best = 1 << 30, bj = -1;
            for (int j2 = 0; j2 < n; ++j2)
                if (tie[j2] < best) { best = tie[j2]; bj = j2; }
            tie[bj] = 1 << 30;
            m_top[bh * NTOP_ + s_outcnt + r] = best;
        }
    }
}

// ---------------------------------------------------------------------------
// Kernel 5: chunked attention partials (flash-style).
// ---------------------------------------------------------------------------
__global__ __launch_bounds__(256) void attn_part_kernel(
    const float* __restrict__ q, const float* __restrict__ k,
    const float* __restrict__ v, const int* __restrict__ m_top,
    float* __restrict__ mx_p, float* __restrict__ sm_p, float* __restrict__ ctx_p)
{
    const int chunk = blockIdx.x;
    const int bh    = blockIdx.y;
    const int t = threadIdx.x;

    __shared__ __align__(16) float  Qs[NTOP_][64];
    __shared__ float4 Ks4[CHUNK_ * 16];
    __shared__ __align__(16) float  Vs[CHUNK_][64];
    __shared__ float  S[NTOP_][CHUNK_];

    for (int i = t; i < NTOP_ * 16; i += 256) {
        int qi = i >> 4, cc = i & 15;
        int l = m_top[bh * NTOP_ + qi];
        *reinterpret_cast<float4*>(&Qs[qi][cc << 2]) =
            *reinterpret_cast<const float4*>(&q[(bh * L_ + l) * HD_ + (cc << 2)]);
    }
    const int base = (bh * L_ + chunk * CHUNK_) * HD_;
    for (int i = t; i < CHUNK_ * 16; i += 256) {
        int r = i >> 4, cc = i & 15;
        Ks4[r * 16 + (cc ^ (r & 7))] =
            *reinterpret_cast<const float4*>(&k[base + r * HD_ + (cc << 2)]);
        *reinterpret_cast<float4*>(&Vs[r][cc << 2]) =
            *reinterpret_cast<const float4*>(&v[base + r * HD_ + (cc << 2)]);
    }
    __syncthreads();

    for (int o = t; o < NTOP_ * CHUNK_; o += 256) {
        int qi = o >> 6, j = o & (CHUNK_ - 1);
        float acc = 0.f;
        #pragma unroll
        for (int cc = 0; cc < 16; ++cc) {
            float4 kf = Ks4[j * 16 + (cc ^ (j & 7))];
            float4 qf = *reinterpret_cast<const float4*>(&Qs[qi][cc << 2]);
            acc = fmaf(qf.x, kf.x, acc);
            acc = fmaf(qf.y, kf.y, acc);
            acc = fmaf(qf.z, kf.z, acc);
            acc = fmaf(qf.w, kf.w, acc);
        }
        S[qi][j] = acc * 0.125f;
    }
    __syncthreads();

    const int gl = t & 31;
    for (int qi = t >> 5; qi < NTOP_; qi += 8) {
        float v0 = S[qi][gl], v1 = S[qi][gl + 32];
        float mx = fmaxf(v0, v1);
        #pragma unroll
        for (int off = 1; off < 32; off <<= 1) mx = fmaxf(mx, __shfl_xor(mx, off));
        float e0 = __expf(v0 - mx), e1 = __expf(v1 - mx);
        float sm = e0 + e1;
        #pragma unroll
        for (int off = 1; off < 32; off <<= 1) sm += __shfl_xor(sm, off);
        S[qi][gl] = e0; S[qi][gl + 32] = e1;
        if (gl == 0) {
            mx_p[(bh * NCH_ + chunk) * NTOP_ + qi] = mx;
            sm_p[(bh * NCH_ + chunk) * NTOP_ + qi] = sm;
        }
    }
    __syncthreads();

    for (int o = t; o < NTOP_ * HD_; o += 256) {
        int qi = o >> 6, d = o & 63;
        float acc = 0.f;
        #pragma unroll 8
        for (int j = 0; j < CHUNK_; ++j) acc = fmaf(S[qi][j], Vs[j][d], acc);
        ctx_p[((bh * NCH_ + chunk) * NTOP_ + qi) * HD_ + d] = acc;
    }
}

// ---------------------------------------------------------------------------
// Kernel 6: broadcast-fill out with base_out[b]
// ---------------------------------------------------------------------------
__global__ __launch_bounds__(256) void fill_kernel(
    const float* __restrict__ base_out, float* __restrict__ out)
{
    const int i = blockIdx.x * 256 + threadIdx.x;
    if (i >= NROW_ * (HID_ / 4)) return;
    const int j4  = i & 127;
    const int row = i >> 7;
    const int b   = row >> 11;
    reinterpret_cast<float4*>(out)[i] =
        reinterpret_cast<const float4*>(base_out)[b * 128 + j4];
}

// ---------------------------------------------------------------------------
// Kernel 7: fused combine + delta scatter.
// ---------------------------------------------------------------------------
__global__ __launch_bounds__(256) void combscat_kernel(
    const float* __restrict__ mx_p, const float* __restrict__ sm_p,
    const float* __restrict__ ctx_p, const float* __restrict__ vmean,
    const int* __restrict__ m_top, const float* __restrict__ Wo,
    float* __restrict__ out)
{
    const int bq = blockIdx.x;
    const int bh = bq / NTOP_, qi = bq % NTOP_;
    const int b = bh >> 3, h = bh & 7;
    const int t = threadIdx.x;
    const int g = t >> 6, d = t & 63;

    __shared__ float Mg[4], Dg[4];
    __shared__ float Ag[4][64];
    __shared__ float delta[64];

    float mxs[8];
    #pragma unroll
    for (int c8 = 0; c8 < 8; ++c8)
        mxs[c8] = mx_p[(bh * NCH_ + g * 8 + c8) * NTOP_ + qi];
    float M = mxs[0];
    #pragma unroll
    for (int c8 = 1; c8 < 8; ++c8) M = fmaxf(M, mxs[c8]);
    float den = 0.f, acc = 0.f;
    #pragma unroll
    for (int c8 = 0; c8 < 8; ++c8) {
        const int c = g * 8 + c8;
        const float w = __expf(mxs[c8] - M);
        den = fmaf(sm_p[(bh * NCH_ + c) * NTOP_ + qi], w, den);
        acc = fmaf(ctx_p[((bh * NCH_ + c) * NTOP_ + qi) * HD_ + d], w, acc);
    }
    if (d == 0) { Mg[g] = M; Dg[g] = den; }
    Ag[g][d] = acc;
    __syncthreads();
    if (t < 64) {
        const float MM = fmaxf(fmaxf(Mg[0], Mg[1]), fmaxf(Mg[2], Mg[3]));
        float dd = 0.f, aa = 0.f;
        #pragma unroll
        for (int gg = 0; gg < 4; ++gg) {
            const float w = __expf(Mg[gg] - MM);
            dd = fmaf(Dg[gg], w, dd);
            aa = fmaf(Ag[gg][t], w, aa);
        }
        delta[t] = aa / dd - vmean[bh * HD_ + t];
    }
    __syncthreads();
    const int l = m_top[bh * NTOP_ + qi];
    for (int j = t; j < HID_; j += 256) {
        float a2 = 0.f;
        #pragma unroll
        for (int c = 0; c < HD_; c += 4) {
            float4 w = *reinterpret_cast<const float4*>(&Wo[(size_t)j * HID_ + h * HD_ + c]);
            a2 = fmaf(delta[c + 0], w.x, a2);
            a2 = fmaf(delta[c + 1], w.y, a2);
            a2 = fmaf(delta[c + 2], w.z, a2);
            a2 = fmaf(delta[c + 3], w.w, a2);
        }
        atomicAdd(&out[((size_t)(b * L_ + l)) * HID_ + j], a2);
    }
}

// ---------------------------------------------------------------------------
extern "C" void kernel_launch(void* const* d_in, const int* in_sizes, int n_in,
                              void* d_out, int out_size, void* d_ws, size_t ws_size,
                              hipStream_t stream)
{
    const float* hs  = (const float*)d_in[0];
    const int*   idx = (const int*)  d_in[1];
    const float* Wq  = (const float*)d_in[2];
    const float* bq  = (const float*)d_in[3];
    const float* Wk  = (const float*)d_in[4];
    const float* bk  = (const float*)d_in[5];
    const float* Wv  = (const float*)d_in[6];
    const float* bv  = (const float*)d_in[7];
    const float* Wo  = (const float*)d_in[8];
    const float* bo  = (const float*)d_in[9];
    float* out = (float*)d_out;

    float* ws = (float*)d_ws;
    const size_t OFF_Q      = 0;
    const size_t OFF_K      = OFF_Q + (size_t)NBH_ * L_ * HD_;
    const size_t OFF_V      = OFF_K + (size_t)NBH_ * L_ * HD_;
    const size_t OFF_M      = OFF_V + (size_t)NBH_ * L_ * HD_;
    const size_t OFF_VMP    = OFF_M + (size_t)NBH_ * L_;
    const size_t OFF_VMEAN  = OFF_VMP + (size_t)NTILE_ * NH_ * HD_;
    const size_t OFF_MXP    = OFF_VMEAN + (size_t)NBH_ * HD_;
    const size_t OFF_SMP    = OFF_MXP + (size_t)NBH_ * NCH_ * NTOP_;
    const size_t OFF_CTXP   = OFF_SMP + (size_t)NBH_ * NCH_ * NTOP_;
    const size_t OFF_BASE   = OFF_CTXP + (size_t)NBH_ * NCH_ * NTOP_ * HD_;
    const size_t OFF_TOP    = OFF_BASE + (size_t)B_ * HID_;

    float* q_      = ws + OFF_Q;
    float* k_      = ws + OFF_K;
    float* v_      = ws + OFF_V;
    float* m_      = ws + OFF_M;
    float* vmp_    = ws + OFF_VMP;
    float* vmean_  = ws + OFF_VMEAN;
    float* mxp_    = ws + OFF_MXP;
    float* smp_    = ws + OFF_SMP;
    float* ctxp_   = ws + OFF_CTXP;
    float* base_   = ws + OFF_BASE;
    int*   mtop_   = (int*)(ws + OFF_TOP);

    proj_kernel<<<dim3(NROW_ / 64, NH_), 256, 0, stream>>>(
        hs, Wq, bq, Wk, bk, Wv, bv, q_, k_, v_, vmp_);
    base_kernel<<<B_, 512, 0, stream>>>(vmp_, Wo, bo, vmean_, base_);
    sample_m_kernel<<<(NBH_ * L_) / 4, 256, 0, stream>>>(q_, k_, idx, m_);
    topk_kernel<<<NBH_, 256, 0, stream>>>(m_, mtop_);
    attn_part_kernel<<<dim3(NCH_, NBH_), 256, 0, stream>>>(
        q_, k_, v_, mtop_, mxp_, smp_, ctxp_);
    fill_kernel<<<(NROW_ * (HID_ / 4) + 255) / 256, 256, 0, stream>>>(base_, out);
    combscat_kernel<<<NBH_ * NTOP_, 256, 0, stream>>>(
        mxp_, smp_, ctxp_, vmean_, mtop_, Wo, out);
}

// Round 14
// 234.281 us; speedup vs baseline: 7.4822x; 1.1016x over previous
//
#include <hip/hip_runtime.h>
#include <hip/hip_bf16.h>
#include <math.h>

// Problem constants
#define B_   2
#define L_   2048
#define HID_ 512
#define NH_  8
#define HD_  64
#define SK_  40
#define NTOP_ 40
#define NBH_ (B_ * NH_)        // 16
#define NROW_ (B_ * L_)        // 4096
#define CHUNK_ 64
#define NCH_ (L_ / CHUNK_)     // 32
#define NTILE_ 64              // 4096/64 row tiles

// ---------------------------------------------------------------------------
// Kernel 1: QKV-merged projection, 64-row tiles (round-11 measured: 89.7 us,
// plateau of the family; kept as-is this round — change under test is kernel
// count, not proj).
// ---------------------------------------------------------------------------
__global__ __launch_bounds__(256, 2) void proj_kernel(
    const float* __restrict__ A,
    const float* __restrict__ Wq, const float* __restrict__ bq,
    const float* __restrict__ Wk, const float* __restrict__ bk,
    const float* __restrict__ Wv, const float* __restrict__ bv,
    float* __restrict__ qo, float* __restrict__ ko, float* __restrict__ vo,
    float* __restrict__ vmp)
{
    __shared__ __align__(16) float As[32][68];       // [k][swizzled 64 rows]
    __shared__ __align__(16) float Bs[3][32][68];    // [w][k][swizzled 64 cols]
    __shared__ float red[16][64];                    // vmean partial reduce

    const float* Ws[3]  = {Wq, Wk, Wv};
    const float* bs3[3] = {bq, bk, bv};
    float*       os3[3] = {qo, ko, vo};

    const int t    = threadIdx.x;
    const int row0 = blockIdx.x * 64;
    const int h    = blockIdx.y;
    const int col0 = h * 64;
    const int ry   = t >> 4;              // 0..15 : rows ry*4 .. +3
    const int cx   = t & 15;              // 0..15 : cols cx*4 .. +3
    const int a_k4 = t & 7;               // float4-group along k
    const int sub  = t >> 3;              // 0..31

    float acc[3][4][4] = {};
    float4 pa[2], pb[3][2];

    #pragma unroll
    for (int i = 0; i < 2; ++i)
        pa[i] = *reinterpret_cast<const float4*>(
            &A[(size_t)(row0 + i * 32 + sub) * HID_ + (a_k4 << 2)]);
    #pragma unroll
    for (int w = 0; w < 3; ++w)
        #pragma unroll
        for (int i = 0; i < 2; ++i)
            pb[w][i] = *reinterpret_cast<const float4*>(
                &Ws[w][(size_t)(col0 + i * 32 + sub) * HID_ + (a_k4 << 2)]);

    for (int ks = 0; ks < 16; ++ks) {
        #pragma unroll
        for (int i = 0; i < 2; ++i) {
            const int a_row = i * 32 + sub;
            const int slot = (a_row >> 2) ^ a_k4;
            float* p = &As[a_k4 << 2][slot * 4 + (a_row & 3)];
            p[0 * 68] = pa[i].x; p[1 * 68] = pa[i].y;
            p[2 * 68] = pa[i].z; p[3 * 68] = pa[i].w;
        }
        #pragma unroll
        for (int w = 0; w < 3; ++w)
            #pragma unroll
            for (int i = 0; i < 2; ++i) {
                const int b_col = i * 32 + sub;
                const int slot = (b_col >> 2) ^ a_k4;
                float* p = &Bs[w][a_k4 << 2][slot * 4 + (b_col & 3)];
                p[0 * 68] = pb[w][i].x; p[1 * 68] = pb[w][i].y;
                p[2 * 68] = pb[w][i].z; p[3 * 68] = pb[w][i].w;
            }
        __syncthreads();

        if (ks < 15) {
            const int k0 = (ks + 1) * 32;
            #pragma unroll
            for (int i = 0; i < 2; ++i)
                pa[i] = *reinterpret_cast<const float4*>(
                    &A[(size_t)(row0 + i * 32 + sub) * HID_ + k0 + (a_k4 << 2)]);
            #pragma unroll
            for (int w = 0; w < 3; ++w)
                #pragma unroll
                for (int i = 0; i < 2; ++i)
                    pb[w][i] = *reinterpret_cast<const float4*>(
                        &Ws[w][(size_t)(col0 + i * 32 + sub) * HID_ + k0 + (a_k4 << 2)]);
        }

        #pragma unroll
        for (int kk = 0; kk < 32; ++kk) {
            const int v = kk >> 2;
            const float4 a0 = *reinterpret_cast<const float4*>(
                &As[kk][(ry ^ v) << 2]);
            const float as[4] = {a0.x, a0.y, a0.z, a0.w};
            #pragma unroll
            for (int w = 0; w < 3; ++w) {
                const float4 b0 = *reinterpret_cast<const float4*>(
                    &Bs[w][kk][(cx ^ v) << 2]);
                #pragma unroll
                for (int i = 0; i < 4; ++i) {
                    acc[w][i][0] = fmaf(as[i], b0.x, acc[w][i][0]);
                    acc[w][i][1] = fmaf(as[i], b0.y, acc[w][i][1]);
                    acc[w][i][2] = fmaf(as[i], b0.z, acc[w][i][2]);
                    acc[w][i][3] = fmaf(as[i], b0.w, acc[w][i][3]);
                }
            }
        }
        __syncthreads();
    }

    const int b_ = row0 >> 11;
    float4 bbv;
    #pragma unroll
    for (int w = 0; w < 3; ++w) {
        const float4 bb = *reinterpret_cast<const float4*>(&bs3[w][col0 + (cx << 2)]);
        if (w == 2) bbv = bb;
        #pragma unroll
        for (int i = 0; i < 4; ++i) {
            const int row = row0 + ry * 4 + i;
            const int l   = row & (L_ - 1);
            float4 ob;
            ob.x = acc[w][i][0] + bb.x;
            ob.y = acc[w][i][1] + bb.y;
            ob.z = acc[w][i][2] + bb.z;
            ob.w = acc[w][i][3] + bb.w;
            *reinterpret_cast<float4*>(
                &os3[w][(((size_t)(b_ * NH_ + h)) * L_ + l) * HD_ + (cx << 2)]) = ob;
        }
    }

    #pragma unroll
    for (int j = 0; j < 4; ++j) {
        float s_ = 0.f;
        #pragma unroll
        for (int i = 0; i < 4; ++i) s_ += acc[2][i][j];
        const float bj = (j == 0) ? bbv.x : (j == 1) ? bbv.y : (j == 2) ? bbv.z : bbv.w;
        red[ry][(cx << 2) + j] = s_ + 4.f * bj;
    }
    __syncthreads();
    if (t < 64) {
        float s_ = 0.f;
        #pragma unroll
        for (int r = 0; r < 16; ++r) s_ += red[r][t];
        vmp[((size_t)blockIdx.x * NH_ + h) * HD_ + t] = s_;    // incl. 64*bias
    }
}

// ---------------------------------------------------------------------------
// Kernel 2: sampled scores (all blocks) + FUSED vmean/base (blocks 0..B_-1).
// m[b,h,l] = max_s(q.k_samp) - sum_s(q.k_samp)/L.
// Blocks 0,1 first reduce vmp -> vmean[b], then base_out[b,j] = vm.Wo[j]+bo.
// ---------------------------------------------------------------------------
__global__ __launch_bounds__(256) void sample_m_kernel(
    const float* __restrict__ q, const float* __restrict__ k,
    const int* __restrict__ idx, float* __restrict__ m,
    const float* __restrict__ vmp, const float* __restrict__ Wo,
    const float* __restrict__ bo, float* __restrict__ vmean,
    float* __restrict__ base_out)
{
    __shared__ float vm[HID_];
    const int t = threadIdx.x;

    if (blockIdx.x < B_) {                 // fused vmean + base (2 blocks)
        const int b = blockIdx.x;
        #pragma unroll
        for (int jj = 0; jj < 2; ++jj) {
            const int j = t + jj * 256;
            float s = 0.f;
            #pragma unroll
            for (int tl = 0; tl < 32; ++tl)
                s += vmp[(size_t)(b * 32 + tl) * HID_ + j];
            const float mv = s * (1.0f / (float)L_);
            vmean[b * HID_ + j] = mv;
            vm[j] = mv;
        }
        __syncthreads();
        #pragma unroll
        for (int jj = 0; jj < 2; ++jj) {
            const int j = t + jj * 256;
            float acc = bo[j];
            for (int c = 0; c < HID_; c += 4) {
                float4 w = *reinterpret_cast<const float4*>(&Wo[(size_t)j * HID_ + c]);
                acc = fmaf(vm[c + 0], w.x, acc);
                acc = fmaf(vm[c + 1], w.y, acc);
                acc = fmaf(vm[c + 2], w.z, acc);
                acc = fmaf(vm[c + 3], w.w, acc);
            }
            base_out[b * HID_ + j] = acc;
        }
    }

    const int wid  = blockIdx.x * 4 + (t >> 6);
    const int lane = t & 63;
    const int bh = wid >> 11;
    const int l  = wid & (L_ - 1);
    const int grp = lane >> 4, gl = lane & 15;

    const float4 qf = *reinterpret_cast<const float4*>(&q[(bh * L_ + l) * HD_ + (gl << 2)]);

    float mx = -INFINITY, sm = 0.f;
    #pragma unroll
    for (int it = 0; it < 10; ++it) {
        const int s  = it * 4 + grp;
        const int ki = idx[l * SK_ + s];
        const float4 kf = *reinterpret_cast<const float4*>(&k[(bh * L_ + ki) * HD_ + (gl << 2)]);
        float p = qf.x * kf.x + qf.y * kf.y + qf.z * kf.z + qf.w * kf.w;
        p += __shfl_xor(p, 1);
        p += __shfl_xor(p, 2);
        p += __shfl_xor(p, 4);
        p += __shfl_xor(p, 8);
        mx = fmaxf(mx, p);
        sm += p;
    }
    mx = fmaxf(mx, __shfl_xor(mx, 16));
    mx = fmaxf(mx, __shfl_xor(mx, 32));
    sm += __shfl_xor(sm, 16);
    sm += __shfl_xor(sm, 32);
    if (lane == 0) m[bh * L_ + l] = mx - sm * (1.0f / (float)L_);
}

// ---------------------------------------------------------------------------
// Kernel 3: top-40 per (b,h) via 32-round bitwise binary search (unchanged).
// ---------------------------------------------------------------------------
__global__ __launch_bounds__(256) void topk_kernel(
    const float* __restrict__ m, int* __restrict__ m_top)
{
    const int bh = blockIdx.x;
    const int t  = threadIdx.x;
    const int lane = t & 63, wv = t >> 6;

    unsigned xv[8];
    #pragma unroll
    for (int i = 0; i < 8; ++i) {
        unsigned x = __float_as_uint(m[bh * L_ + i * 256 + t]);
        xv[i] = (x & 0x80000000u) ? ~x : (x | 0x80000000u);
    }

    __shared__ int cnt[2][4];
    __shared__ int s_outcnt, s_tieCnt;
    __shared__ int tie[256];
    if (t == 0) { s_outcnt = 0; s_tieCnt = 0; }

    unsigned pref = 0;
    for (int bit = 31; bit >= 0; --bit) {
        const unsigned test = pref | (1u << bit);
        int c = 0;
        #pragma unroll
        for (int i = 0; i < 8; ++i) c += (xv[i] >= test);
        #pragma unroll
        for (int off = 1; off < 64; off <<= 1) c += __shfl_xor(c, off);
        if (lane == 0) cnt[bit & 1][wv] = c;
        __syncthreads();
        const int tot = cnt[bit & 1][0] + cnt[bit & 1][1]
                      + cnt[bit & 1][2] + cnt[bit & 1][3];
        if (tot >= NTOP_) pref = test;
    }
    const unsigned V = pref;

    #pragma unroll
    for (int i = 0; i < 8; ++i) {
        const unsigned x = xv[i];
        const int idxv = i * 256 + t;
        if (x > V) {
            const int p = atomicAdd(&s_outcnt, 1);
            m_top[bh * NTOP_ + p] = idxv;
        } else if (x == V) {
            const int p = atomicAdd(&s_tieCnt, 1);
            if (p < 256) tie[p] = idxv;
        }
    }
    __syncthreads();
    if (t == 0) {
        const int rem = NTOP_ - s_outcnt;
        int n = s_tieCnt; if (n > 256) n = 256;
        for (int r = 0; r < rem; ++r) {
            int best = 1 << 30, bj = -1;
            for (int j2 = 0; j2 < n; ++j2)
                if (tie[j2] < best) { best = tie[j2]; bj = j2; }
            tie[bj] = 1 << 30;
            m_top[bh * NTOP_ + s_outcnt + r] = best;
        }
    }
}

// ---------------------------------------------------------------------------
// Kernel 4: chunked attention partials + FUSED broadcast-fill of out.
// Each of 512 blocks first writes its 16KB slice of out = base_out[b]
// (base ready since kernel 2; combscat's atomics run in a later kernel).
// Phase 3 vectorized: (qi, d4) float4 mapping (4x fewer LDS instructions).
// ---------------------------------------------------------------------------
__global__ __launch_bounds__(256) void attn_part_kernel(
    const float* __restrict__ q, const float* __restrict__ k,
    const float* __restrict__ v, const int* __restrict__ m_top,
    const float* __restrict__ base_out, float* __restrict__ out,
    float* __restrict__ mx_p, float* __restrict__ sm_p, float* __restrict__ ctx_p)
{
    const int chunk = blockIdx.x;
    const int bh    = blockIdx.y;
    const int t = threadIdx.x;

    // fused broadcast-fill: block f covers float4 indices f*1024 .. +1023
    {
        const int f = bh * NCH_ + chunk;             // 0..511
        const float4* b4 = reinterpret_cast<const float4*>(base_out);
        float4* o4 = reinterpret_cast<float4*>(out);
        #pragma unroll
        for (int k2 = 0; k2 < 4; ++k2) {
            const int i = f * 1024 + k2 * 256 + t;   // < 524288
            const int j4 = i & 127;
            const int b  = i >> 18;                  // row>>11, row=i>>7
            o4[i] = b4[b * 128 + j4];
        }
    }

    __shared__ __align__(16) float  Qs[NTOP_][64];
    __shared__ float4 Ks4[CHUNK_ * 16];
    __shared__ __align__(16) float  Vs[CHUNK_][64];
    __shared__ float  S[NTOP_][CHUNK_];

    for (int i = t; i < NTOP_ * 16; i += 256) {
        int qi = i >> 4, cc = i & 15;
        int l = m_top[bh * NTOP_ + qi];
        *reinterpret_cast<float4*>(&Qs[qi][cc << 2]) =
            *reinterpret_cast<const float4*>(&q[(bh * L_ + l) * HD_ + (cc << 2)]);
    }
    const int base = (bh * L_ + chunk * CHUNK_) * HD_;
    for (int i = t; i < CHUNK_ * 16; i += 256) {
        int r = i >> 4, cc = i & 15;
        Ks4[r * 16 + (cc ^ (r & 7))] =
            *reinterpret_cast<const float4*>(&k[base + r * HD_ + (cc << 2)]);
        *reinterpret_cast<float4*>(&Vs[r][cc << 2]) =
            *reinterpret_cast<const float4*>(&v[base + r * HD_ + (cc << 2)]);
    }
    __syncthreads();

    for (int o = t; o < NTOP_ * CHUNK_; o += 256) {
        int qi = o >> 6, j = o & (CHUNK_ - 1);
        float acc = 0.f;
        #pragma unroll
        for (int cc = 0; cc < 16; ++cc) {
            float4 kf = Ks4[j * 16 + (cc ^ (j & 7))];
            float4 qf = *reinterpret_cast<const float4*>(&Qs[qi][cc << 2]);
            acc = fmaf(qf.x, kf.x, acc);
            acc = fmaf(qf.y, kf.y, acc);
            acc = fmaf(qf.z, kf.z, acc);
            acc = fmaf(qf.w, kf.w, acc);
        }
        S[qi][j] = acc * 0.125f;
    }
    __syncthreads();

    const int gl = t & 31;
    for (int qi = t >> 5; qi < NTOP_; qi += 8) {
        float v0 = S[qi][gl], v1 = S[qi][gl + 32];
        float mx = fmaxf(v0, v1);
        #pragma unroll
        for (int off = 1; off < 32; off <<= 1) mx = fmaxf(mx, __shfl_xor(mx, off));
        float e0 = __expf(v0 - mx), e1 = __expf(v1 - mx);
        float sm = e0 + e1;
        #pragma unroll
        for (int off = 1; off < 32; off <<= 1) sm += __shfl_xor(sm, off);
        S[qi][gl] = e0; S[qi][gl + 32] = e1;
        if (gl == 0) {
            mx_p[(bh * NCH_ + chunk) * NTOP_ + qi] = mx;
            sm_p[(bh * NCH_ + chunk) * NTOP_ + qi] = sm;
        }
    }
    __syncthreads();

    // phase 3 (vectorized): ctx_p[qi][d4..d4+3] = sum_j P[qi][j] * Vs[j][d4..]
    for (int o = t; o < NTOP_ * 16; o += 256) {
        const int qi = o >> 4, d4 = (o & 15) << 2;
        float4 a4 = {0.f, 0.f, 0.f, 0.f};
        #pragma unroll 8
        for (int j = 0; j < CHUNK_; ++j) {
            const float s = S[qi][j];
            const float4 v4 = *reinterpret_cast<const float4*>(&Vs[j][d4]);
            a4.x = fmaf(s, v4.x, a4.x);
            a4.y = fmaf(s, v4.y, a4.y);
            a4.z = fmaf(s, v4.z, a4.z);
            a4.w = fmaf(s, v4.w, a4.w);
        }
        *reinterpret_cast<float4*>(
            &ctx_p[((size_t)(bh * NCH_ + chunk) * NTOP_ + qi) * HD_ + d4]) = a4;
    }
}

// ---------------------------------------------------------------------------
// Kernel 5: fused combine + delta scatter (unchanged).
// ---------------------------------------------------------------------------
__global__ __launch_bounds__(256) void combscat_kernel(
    const float* __restrict__ mx_p, const float* __restrict__ sm_p,
    const float* __restrict__ ctx_p, const float* __restrict__ vmean,
    const int* __restrict__ m_top, const float* __restrict__ Wo,
    float* __restrict__ out)
{
    const int bq = blockIdx.x;
    const int bh = bq / NTOP_, qi = bq % NTOP_;
    const int b = bh >> 3, h = bh & 7;
    const int t = threadIdx.x;
    const int g = t >> 6, d = t & 63;

    __shared__ float Mg[4], Dg[4];
    __shared__ float Ag[4][64];
    __shared__ float delta[64];

    float mxs[8];
    #pragma unroll
    for (int c8 = 0; c8 < 8; ++c8)
        mxs[c8] = mx_p[(bh * NCH_ + g * 8 + c8) * NTOP_ + qi];
    float M = mxs[0];
    #pragma unroll
    for (int c8 = 1; c8 < 8; ++c8) M = fmaxf(M, mxs[c8]);
    float den = 0.f, acc = 0.f;
    #pragma unroll
    for (int c8 = 0; c8 < 8; ++c8) {
        const int c = g * 8 + c8;
        const float w = __expf(mxs[c8] - M);
        den = fmaf(sm_p[(bh * NCH_ + c) * NTOP_ + qi], w, den);
        acc = fmaf(ctx_p[((size_t)(bh * NCH_ + c) * NTOP_ + qi) * HD_ + d], w, acc);
    }
    if (d == 0) { Mg[g] = M; Dg[g] = den; }
    Ag[g][d] = acc;
    __syncthreads();
    if (t < 64) {
        const float MM = fmaxf(fmaxf(Mg[0], Mg[1]), fmaxf(Mg[2], Mg[3]));
        float dd = 0.f, aa = 0.f;
        #pragma unroll
        for (int gg = 0; gg < 4; ++gg) {
            const float w = __expf(Mg[gg] - MM);
            dd = fmaf(Dg[gg], w, dd);
            aa = fmaf(Ag[gg][t], w, aa);
        }
        delta[t] = aa / dd - vmean[bh * HD_ + t];
    }
    __syncthreads();
    const int l = m_top[bh * NTOP_ + qi];
    for (int j = t; j < HID_; j += 256) {
        float a2 = 0.f;
        #pragma unroll
        for (int c = 0; c < HD_; c += 4) {
            float4 w = *reinterpret_cast<const float4*>(&Wo[(size_t)j * HID_ + h * HD_ + c]);
            a2 = fmaf(delta[c + 0], w.x, a2);
            a2 = fmaf(delta[c + 1], w.y, a2);
            a2 = fmaf(delta[c + 2], w.z, a2);
            a2 = fmaf(delta[c + 3], w.w, a2);
        }
        atomicAdd(&out[((size_t)(b * L_ + l)) * HID_ + j], a2);
    }
}

// ---------------------------------------------------------------------------
extern "C" void kernel_launch(void* const* d_in, const int* in_sizes, int n_in,
                              void* d_out, int out_size, void* d_ws, size_t ws_size,
                              hipStream_t stream)
{
    const float* hs  = (const float*)d_in[0];
    const int*   idx = (const int*)  d_in[1];
    const float* Wq  = (const float*)d_in[2];
    const float* bq  = (const float*)d_in[3];
    const float* Wk  = (const float*)d_in[4];
    const float* bk  = (const float*)d_in[5];
    const float* Wv  = (const float*)d_in[6];
    const float* bv  = (const float*)d_in[7];
    const float* Wo  = (const float*)d_in[8];
    const float* bo  = (const float*)d_in[9];
    float* out = (float*)d_out;

    float* ws = (float*)d_ws;
    const size_t OFF_Q      = 0;
    const size_t OFF_K      = OFF_Q + (size_t)NBH_ * L_ * HD_;
    const size_t OFF_V      = OFF_K + (size_t)NBH_ * L_ * HD_;
    const size_t OFF_M      = OFF_V + (size_t)NBH_ * L_ * HD_;
    const size_t OFF_VMP    = OFF_M + (size_t)NBH_ * L_;
    const size_t OFF_VMEAN  = OFF_VMP + (size_t)NTILE_ * NH_ * HD_;
    const size_t OFF_MXP    = OFF_VMEAN + (size_t)NBH_ * HD_;
    const size_t OFF_SMP    = OFF_MXP + (size_t)NBH_ * NCH_ * NTOP_;
    const size_t OFF_CTXP   = OFF_SMP + (size_t)NBH_ * NCH_ * NTOP_;
    const size_t OFF_BASE   = OFF_CTXP + (size_t)NBH_ * NCH_ * NTOP_ * HD_;
    const size_t OFF_TOP    = OFF_BASE + (size_t)B_ * HID_;

    float* q_      = ws + OFF_Q;
    float* k_      = ws + OFF_K;
    float* v_      = ws + OFF_V;
    float* m_      = ws + OFF_M;
    float* vmp_    = ws + OFF_VMP;
    float* vmean_  = ws + OFF_VMEAN;
    float* mxp_    = ws + OFF_MXP;
    float* smp_    = ws + OFF_SMP;
    float* ctxp_   = ws + OFF_CTXP;
    float* base_   = ws + OFF_BASE;
    int*   mtop_   = (int*)(ws + OFF_TOP);

    proj_kernel<<<dim3(NROW_ / 64, NH_), 256, 0, stream>>>(
        hs, Wq, bq, Wk, bk, Wv, bv, q_, k_, v_, vmp_);
    sample_m_kernel<<<(NBH_ * L_) / 4, 256, 0, stream>>>(
        q_, k_, idx, m_, vmp_, Wo, bo, vmean_, base_);
    topk_kernel<<<NBH_, 256, 0, stream>>>(m_, mtop_);
    attn_part_kernel<<<dim3(NCH_, NBH_), 256, 0, stream>>>(
        q_, k_, v_, mtop_, base_, out, mxp_, smp_, ctxp_);
    combscat_kernel<<<NBH_ * NTOP_, 256, 0, stream>>>(
        mxp_, smp_, ctxp_, vmean_, mtop_, Wo, out);
}